// Round 2
// baseline (228.803 us; speedup 1.0000x reference)
//
#include <hip/hip_runtime.h>
#include <hip/hip_bf16.h>
#include <hip/hip_cooperative_groups.h>
#include <math.h>

namespace cg = cooperative_groups;

#define C_CH 256
#define OPAD 260   // obuf row stride (floats); %4==0 keeps float4 writes aligned
#define NTILES 5440
#define FGRID 512

__device__ __forceinline__ float bfu(unsigned short s) {
  union { unsigned u; float f; } v;
  v.u = (unsigned)s << 16;
  return v.f;
}

// ---------------------------------------------------------------------------
// Tile descriptor for the fp32 (C,H,W) -> bf16 (H*W, C) transpose.
// 5440 quarter-tiles of 64 spatial x 64 channels (the R0-proven geometry).
// ---------------------------------------------------------------------------
struct TInfo { const float* src; size_t dstbase; int S; };

__device__ __forceinline__ TInfo tinfo(int b, const float* f0, const float* f1,
                                       const float* f2, const float* f3) {
  TInfo ti; int lg; size_t dstoff; int sb;
  if (b < 4096)      { ti.src = f0; ti.S = 65536; lg = 10; dstoff = 0;     sb = b; }
  else if (b < 5120) { ti.src = f1; ti.S = 16384; lg = 8;  dstoff = 65536; sb = b - 4096; }
  else if (b < 5376) { ti.src = f2; ti.S = 4096;  lg = 6;  dstoff = 81920; sb = b - 5120; }
  else               { ti.src = f3; ti.S = 1024;  lg = 4;  dstoff = 86016; sb = b - 5376; }
  const int nsp_m1 = (1 << lg) - 1;
  const int s0 = (sb & nsp_m1) * 64;
  const int c0 = (sb >> lg) * 64;
  ti.src += (size_t)c0 * ti.S + s0;                  // fold tile origin in
  ti.dstbase = (dstoff + (size_t)s0) * C_CH + c0;    // element offset into tf
  return ti;
}

__device__ __forceinline__ void t_load(const TInfo& ti, float (*tile)[65],
                                       int cl, int sp4) {
  #pragma unroll
  for (int j = 0; j < 2; ++j) {
    const int c = cl + 32 * j;
    const float4 v = *(const float4*)(ti.src + (size_t)c * ti.S + sp4);
    tile[c][sp4 + 0] = v.x;
    tile[c][sp4 + 1] = v.y;
    tile[c][sp4 + 2] = v.z;
    tile[c][sp4 + 3] = v.w;
  }
}

__device__ __forceinline__ void t_store(const TInfo& ti,
                                        unsigned short* __restrict__ tf,
                                        const float (*tile)[65], int spl,
                                        int c4) {
  #pragma unroll
  for (int j = 0; j < 2; ++j) {
    const int sp = spl + 32 * j;
    union { ushort4 u; __hip_bfloat16 h[4]; } p;
    p.h[0] = __float2bfloat16(tile[c4 + 0][sp]);
    p.h[1] = __float2bfloat16(tile[c4 + 1][sp]);
    p.h[2] = __float2bfloat16(tile[c4 + 2][sp]);
    p.h[3] = __float2bfloat16(tile[c4 + 3][sp]);
    *(ushort4*)(tf + ti.dstbase + (size_t)sp * C_CH + c4) = p.u;
  }
}

// ---------------------------------------------------------------------------
// Fused: phase 1 transposes all 4 FPN levels to bf16 (H*W,C) in d_ws with a
// double-buffered tile loop (one barrier per tile, load k+1 overlaps store k);
// grid-wide sync; phase 2 = ROI Align + 2x2 maxpool, one block per proposal.
// 512 blocks x 512 threads, LDS 51.4 KB, VGPR capped at 128 via
// __launch_bounds__(512,4) -> 2 blocks/CU -> exactly 512 co-resident blocks
// (cooperative-launch requirement).
// ---------------------------------------------------------------------------
__global__ __launch_bounds__(512, 4) void fused_all(
    const float* __restrict__ f0, const float* __restrict__ f1,
    const float* __restrict__ f2, const float* __restrict__ f3,
    const float* __restrict__ proposals, unsigned short* __restrict__ tf,
    float* __restrict__ out, int N) {
  __shared__ union {
    float tile[2][64][65];   // 33.3 KB transpose double-buffer
    float obuf[49 * OPAD];   // 51.0 KB roi staging
  } sm;
  __shared__ int xo0[14], xo1[14], yo0[14], yo1[14];
  __shared__ float wxa[14], wxb[14], wya[14], wyb[14];

  const int t = threadIdx.x;

  // ---------------- Phase 1: transpose ----------------
  {
    const int cl = t >> 4;          // 0..31 (load: channel row)
    const int sp4 = (t & 15) * 4;   // 0..60 (load: spatial float4)
    const int spl = t >> 4;         // 0..31 (store: spatial row)
    const int c4 = (t & 15) * 4;    // 0..60 (store: channel quad)

    int b = blockIdx.x;             // grid 512 < 5440, prologue always valid
    TInfo ti = tinfo(b, f0, f1, f2, f3);
    t_load(ti, sm.tile[0], cl, sp4);
    int cur = 0;
    for (;;) {
      const int bn = b + FGRID;
      const bool more = (bn < NTILES);   // block-uniform
      TInfo tin;
      if (more) tin = tinfo(bn, f0, f1, f2, f3);
      __syncthreads();                   // tile[cur] fully written
      if (more) t_load(tin, sm.tile[cur ^ 1], cl, sp4);
      t_store(ti, tf, sm.tile[cur], spl, c4);
      if (!more) break;
      ti = tin;
      b = bn;
      cur ^= 1;
    }
  }

  cg::this_grid().sync();  // all of tf written + visible device-wide

  // ---------------- Phase 2: ROI align + maxpool ----------------
  for (int n = blockIdx.x; n < N; n += FGRID) {
    const int lane = t & 63;
    const int w = t >> 6;  // wave id 0..7

    const float px1 = proposals[n * 4 + 0];
    const float py1 = proposals[n * 4 + 1];
    const float px2 = proposals[n * 4 + 2];
    const float py2 = proposals[n * 4 + 3];
    float lt = 2.0f + log2f(sqrtf((px2 - px1) * (py2 - py1)) / 224.0f);
    int lvl = (int)floorf(lt);
    lvl = lvl < 0 ? 0 : (lvl > 3 ? 3 : lvl);

    const float scales[4] = {0.25f, 0.125f, 0.0625f, 0.03125f};
    const int sizes[4] = {256, 128, 64, 32};
    const int offs[4] = {0, 65536, 81920, 86016};
    const float sc = scales[lvl];
    const int sz = sizes[lvl];

    const float bx1 = px1 * sc, by1 = py1 * sc;
    const float w_unit = ((px2 - px1) * sc / 7.0f) * 0.5f;
    const float h_unit = ((py2 - py1) * sc / 7.0f) * 0.5f;

    if (t < 14) {
      const int i = t;
      float x = bx1 + ((float)i + 0.5f) * w_unit;
      int xf = (int)floorf(x);
      int x0 = min(max(xf, 0), sz - 1);
      int x1 = min(max(xf + 1, 0), sz - 1);
      wxa[i] = (float)x1 - x;  // matches ref incl. clipped extrapolation
      wxb[i] = x - (float)x0;
      xo0[i] = x0 * C_CH;
      xo1[i] = x1 * C_CH;
    } else if (t >= 64 && t < 78) {
      const int i = t - 64;
      float y = by1 + ((float)i + 0.5f) * h_unit;
      int yf = (int)floorf(y);
      int y0 = min(max(yf, 0), sz - 1);
      int y1 = min(max(yf + 1, 0), sz - 1);
      wya[i] = (float)y1 - y;
      wyb[i] = y - (float)y0;
      yo0[i] = y0 * sz * C_CH;
      yo1[i] = y1 * sz * C_CH;
    }
    __syncthreads();

    if (w < 7) {  // wave-uniform: waves 0-6 compute, wave 7 only helps store
      const int oh = w;
      const int gy0 = 2 * oh, gy1 = 2 * oh + 1;
      const unsigned short* base = tf + (size_t)offs[lvl] * C_CH + lane * 4;
      const unsigned short* r00 = base + yo0[gy0];
      const unsigned short* r01 = base + yo1[gy0];
      const unsigned short* r10 = base + yo0[gy1];
      const unsigned short* r11 = base + yo1[gy1];
      const float wy0a = wya[gy0], wy0b = wyb[gy0];
      const float wy1a = wya[gy1], wy1b = wyb[gy1];

      float mm[7][4];
      #pragma unroll
      for (int j = 0; j < 7; ++j)
        #pragma unroll
        for (int k = 0; k < 4; ++k) mm[j][k] = -INFINITY;

      #pragma unroll
      for (int gx = 0; gx < 14; ++gx) {
        const int xa = xo0[gx], xb = xo1[gx];
        const ushort4 A0 = *(const ushort4*)(r00 + xa);
        const ushort4 A1 = *(const ushort4*)(r00 + xb);
        const ushort4 B0 = *(const ushort4*)(r01 + xa);
        const ushort4 B1 = *(const ushort4*)(r01 + xb);
        const ushort4 C0 = *(const ushort4*)(r10 + xa);
        const ushort4 C1 = *(const ushort4*)(r10 + xb);
        const ushort4 D0 = *(const ushort4*)(r11 + xa);
        const ushort4 D1 = *(const ushort4*)(r11 + xb);
        const float fa = wxa[gx], fb = wxb[gx];
        const int j = gx >> 1;
        const unsigned short* a0 = (const unsigned short*)&A0;
        const unsigned short* a1 = (const unsigned short*)&A1;
        const unsigned short* b0 = (const unsigned short*)&B0;
        const unsigned short* b1 = (const unsigned short*)&B1;
        const unsigned short* c0 = (const unsigned short*)&C0;
        const unsigned short* c1 = (const unsigned short*)&C1;
        const unsigned short* d0 = (const unsigned short*)&D0;
        const unsigned short* d1 = (const unsigned short*)&D1;
        #pragma unroll
        for (int k = 0; k < 4; ++k) {
          const float h00 = fa * bfu(a0[k]) + fb * bfu(a1[k]);
          const float h01 = fa * bfu(b0[k]) + fb * bfu(b1[k]);
          const float va = wy0a * h00 + wy0b * h01;
          const float h10 = fa * bfu(c0[k]) + fb * bfu(c1[k]);
          const float h11 = fa * bfu(d0[k]) + fb * bfu(d1[k]);
          const float vb = wy1a * h10 + wy1b * h11;
          mm[j][k] = fmaxf(mm[j][k], fmaxf(va, vb));
        }
      }

      // Stage: obuf[p][c], p = oh*7+ow; wave writes one contiguous 1 KB row
      // per ow -> conflict-free ds_write_b128.
      #pragma unroll
      for (int ow = 0; ow < 7; ++ow) {
        float4 v = make_float4(mm[ow][0], mm[ow][1], mm[ow][2], mm[ow][3]);
        *(float4*)&sm.obuf[(oh * 7 + ow) * OPAD + lane * 4] = v;
      }
    }
    __syncthreads();

    // Contiguous coalesced block store: out[n*12544 + i], i = c*49 + p.
    float* ob = out + (size_t)n * (C_CH * 49);
    for (int i = t; i < C_CH * 49; i += 512) {
      const unsigned c = (unsigned)i / 49u;
      const unsigned p = (unsigned)i - c * 49u;
      ob[i] = sm.obuf[p * OPAD + c];
    }
    __syncthreads();  // tables/obuf reusable for next n (if any)
  }
}

// ---------------------------------------------------------------------------
// Fallback path A (cooperative launch unavailable): the R0-proven pair.
// ---------------------------------------------------------------------------
__global__ __launch_bounds__(256) void transpose_all(
    const float* __restrict__ f0, const float* __restrict__ f1,
    const float* __restrict__ f2, const float* __restrict__ f3,
    __hip_bfloat16* __restrict__ tf) {
  __shared__ float tile[64][65];
  const int b = blockIdx.x;  // 5440 total
  const float* src;
  int S, lg;
  size_t dstoff;
  int sb;
  if (b < 4096) {
    src = f0; S = 65536; lg = 10; dstoff = 0;     sb = b;
  } else if (b < 5120) {
    src = f1; S = 16384; lg = 8;  dstoff = 65536; sb = b - 4096;
  } else if (b < 5376) {
    src = f2; S = 4096;  lg = 6;  dstoff = 81920; sb = b - 5120;
  } else {
    src = f3; S = 1024;  lg = 4;  dstoff = 86016; sb = b - 5376;
  }
  const int nsp_m1 = (1 << lg) - 1;
  const int s0 = (sb & nsp_m1) * 64;
  const int c0 = (sb >> lg) * 64;

  const int t = threadIdx.x;
  {
    const int cl = t >> 4;
    const int sp4 = (t & 15) * 4;
    #pragma unroll
    for (int j = 0; j < 4; ++j) {
      const int c = cl + 16 * j;
      const float4 v = *(const float4*)(src + (size_t)(c0 + c) * S + s0 + sp4);
      tile[c][sp4 + 0] = v.x;
      tile[c][sp4 + 1] = v.y;
      tile[c][sp4 + 2] = v.z;
      tile[c][sp4 + 3] = v.w;
    }
  }
  __syncthreads();
  {
    const int spl = t >> 4;
    const int c4 = (t & 15) * 4;
    __hip_bfloat16* dst = tf + (dstoff + (size_t)s0) * C_CH + c0;
    #pragma unroll
    for (int j = 0; j < 4; ++j) {
      const int sp = spl + 16 * j;
      union { ushort4 u; __hip_bfloat16 h[4]; } p;
      p.h[0] = __float2bfloat16(tile[c4 + 0][sp]);
      p.h[1] = __float2bfloat16(tile[c4 + 1][sp]);
      p.h[2] = __float2bfloat16(tile[c4 + 2][sp]);
      p.h[3] = __float2bfloat16(tile[c4 + 3][sp]);
      *(ushort4*)(dst + (size_t)sp * C_CH + c4) = p.u;
    }
  }
}

__global__ __launch_bounds__(512) void roi_bf16(
    const unsigned short* __restrict__ tf,
    const float* __restrict__ proposals, float* __restrict__ out) {
  __shared__ int xo0[14], xo1[14], yo0[14], yo1[14];
  __shared__ float wxa[14], wxb[14], wya[14], wyb[14];
  __shared__ float obuf[49 * OPAD];

  const int n = blockIdx.x;
  const int t = threadIdx.x;
  const int lane = t & 63;
  const int w = t >> 6;

  const float px1 = proposals[n * 4 + 0];
  const float py1 = proposals[n * 4 + 1];
  const float px2 = proposals[n * 4 + 2];
  const float py2 = proposals[n * 4 + 3];
  float lt = 2.0f + log2f(sqrtf((px2 - px1) * (py2 - py1)) / 224.0f);
  int lvl = (int)floorf(lt);
  lvl = lvl < 0 ? 0 : (lvl > 3 ? 3 : lvl);

  const float scales[4] = {0.25f, 0.125f, 0.0625f, 0.03125f};
  const int sizes[4] = {256, 128, 64, 32};
  const int offs[4] = {0, 65536, 81920, 86016};
  const float sc = scales[lvl];
  const int sz = sizes[lvl];

  const float bx1 = px1 * sc, by1 = py1 * sc;
  const float w_unit = ((px2 - px1) * sc / 7.0f) * 0.5f;
  const float h_unit = ((py2 - py1) * sc / 7.0f) * 0.5f;

  if (t < 14) {
    const int i = t;
    float x = bx1 + ((float)i + 0.5f) * w_unit;
    int xf = (int)floorf(x);
    int x0 = min(max(xf, 0), sz - 1);
    int x1 = min(max(xf + 1, 0), sz - 1);
    wxa[i] = (float)x1 - x;
    wxb[i] = x - (float)x0;
    xo0[i] = x0 * C_CH;
    xo1[i] = x1 * C_CH;
  } else if (t >= 64 && t < 78) {
    const int i = t - 64;
    float y = by1 + ((float)i + 0.5f) * h_unit;
    int yf = (int)floorf(y);
    int y0 = min(max(yf, 0), sz - 1);
    int y1 = min(max(yf + 1, 0), sz - 1);
    wya[i] = (float)y1 - y;
    wyb[i] = y - (float)y0;
    yo0[i] = y0 * sz * C_CH;
    yo1[i] = y1 * sz * C_CH;
  }
  __syncthreads();

  if (w < 7) {
    const int oh = w;
    const int gy0 = 2 * oh, gy1 = 2 * oh + 1;
    const unsigned short* base = tf + (size_t)offs[lvl] * C_CH + lane * 4;
    const unsigned short* r00 = base + yo0[gy0];
    const unsigned short* r01 = base + yo1[gy0];
    const unsigned short* r10 = base + yo0[gy1];
    const unsigned short* r11 = base + yo1[gy1];
    const float wy0a = wya[gy0], wy0b = wyb[gy0];
    const float wy1a = wya[gy1], wy1b = wyb[gy1];

    float mm[7][4];
    #pragma unroll
    for (int j = 0; j < 7; ++j)
      #pragma unroll
      for (int k = 0; k < 4; ++k) mm[j][k] = -INFINITY;

    #pragma unroll
    for (int gx = 0; gx < 14; ++gx) {
      const int xa = xo0[gx], xb = xo1[gx];
      const ushort4 A0 = *(const ushort4*)(r00 + xa);
      const ushort4 A1 = *(const ushort4*)(r00 + xb);
      const ushort4 B0 = *(const ushort4*)(r01 + xa);
      const ushort4 B1 = *(const ushort4*)(r01 + xb);
      const ushort4 C0 = *(const ushort4*)(r10 + xa);
      const ushort4 C1 = *(const ushort4*)(r10 + xb);
      const ushort4 D0 = *(const ushort4*)(r11 + xa);
      const ushort4 D1 = *(const ushort4*)(r11 + xb);
      const float fa = wxa[gx], fb = wxb[gx];
      const int j = gx >> 1;
      const unsigned short* a0 = (const unsigned short*)&A0;
      const unsigned short* a1 = (const unsigned short*)&A1;
      const unsigned short* b0 = (const unsigned short*)&B0;
      const unsigned short* b1 = (const unsigned short*)&B1;
      const unsigned short* c0 = (const unsigned short*)&C0;
      const unsigned short* c1 = (const unsigned short*)&C1;
      const unsigned short* d0 = (const unsigned short*)&D0;
      const unsigned short* d1 = (const unsigned short*)&D1;
      #pragma unroll
      for (int k = 0; k < 4; ++k) {
        const float h00 = fa * bfu(a0[k]) + fb * bfu(a1[k]);
        const float h01 = fa * bfu(b0[k]) + fb * bfu(b1[k]);
        const float va = wy0a * h00 + wy0b * h01;
        const float h10 = fa * bfu(c0[k]) + fb * bfu(c1[k]);
        const float h11 = fa * bfu(d0[k]) + fb * bfu(d1[k]);
        const float vb = wy1a * h10 + wy1b * h11;
        mm[j][k] = fmaxf(mm[j][k], fmaxf(va, vb));
      }
    }

    #pragma unroll
    for (int ow = 0; ow < 7; ++ow) {
      float4 v = make_float4(mm[ow][0], mm[ow][1], mm[ow][2], mm[ow][3]);
      *(float4*)&obuf[(oh * 7 + ow) * OPAD + lane * 4] = v;
    }
  }
  __syncthreads();

  float* ob = out + (size_t)n * (C_CH * 49);
  for (int i = t; i < C_CH * 49; i += 512) {
    const unsigned c = (unsigned)i / 49u;
    const unsigned p = (unsigned)i - c * 49u;
    ob[i] = obuf[p * OPAD + c];
  }
}

// ---------------------------------------------------------------------------
// Fallback path B (no workspace): direct (C,H,W) reads. Correctness-only.
// ---------------------------------------------------------------------------
__global__ __launch_bounds__(64) void roi_fallback(
    const float* __restrict__ f0, const float* __restrict__ f1,
    const float* __restrict__ f2, const float* __restrict__ f3,
    const float* __restrict__ proposals, float* __restrict__ out) {
  __shared__ int xo0[14], xo1[14], yo0[14], yo1[14];
  __shared__ float wxa[14], wxb[14], wya[14], wyb[14];
  const int n = blockIdx.x;
  const int cblk = blockIdx.y;
  const int lane = threadIdx.x;
  const int c = cblk * 64 + lane;
  const float px1 = proposals[n * 4 + 0];
  const float py1 = proposals[n * 4 + 1];
  const float px2 = proposals[n * 4 + 2];
  const float py2 = proposals[n * 4 + 3];
  float lt = 2.0f + log2f(sqrtf((px2 - px1) * (py2 - py1)) / 224.0f);
  int lvl = (int)floorf(lt);
  lvl = lvl < 0 ? 0 : (lvl > 3 ? 3 : lvl);
  const float scales[4] = {0.25f, 0.125f, 0.0625f, 0.03125f};
  const int sizes[4] = {256, 128, 64, 32};
  const float sc = scales[lvl];
  const int sz = sizes[lvl];
  const float bx1 = px1 * sc, by1 = py1 * sc;
  const float w_unit = ((px2 - px1) * sc / 7.0f) * 0.5f;
  const float h_unit = ((py2 - py1) * sc / 7.0f) * 0.5f;
  if (lane < 14) {
    float x = bx1 + ((float)lane + 0.5f) * w_unit;
    int xf = (int)floorf(x);
    int x0 = min(max(xf, 0), sz - 1);
    int x1 = min(max(xf + 1, 0), sz - 1);
    wxa[lane] = (float)x1 - x;
    wxb[lane] = x - (float)x0;
    xo0[lane] = x0;
    xo1[lane] = x1;
  } else if (lane >= 32 && lane < 46) {
    const int i = lane - 32;
    float y = by1 + ((float)i + 0.5f) * h_unit;
    int yf = (int)floorf(y);
    int y0 = min(max(yf, 0), sz - 1);
    int y1 = min(max(yf + 1, 0), sz - 1);
    wya[i] = (float)y1 - y;
    wyb[i] = y - (float)y0;
    yo0[i] = y0 * sz;
    yo1[i] = y1 * sz;
  }
  __syncthreads();
  const float* fl = (lvl == 0) ? f0 : (lvl == 1) ? f1 : (lvl == 2) ? f2 : f3;
  const float* base = fl + (size_t)c * sz * sz;
  for (int oh = 0; oh < 7; ++oh) {
    float mm[7];
    #pragma unroll
    for (int ow = 0; ow < 7; ++ow) mm[ow] = -INFINITY;
    #pragma unroll
    for (int sy = 0; sy < 2; ++sy) {
      const int gy = oh * 2 + sy;
      const float* r0 = base + yo0[gy];
      const float* r1 = base + yo1[gy];
      const float wy0 = wya[gy], wy1 = wyb[gy];
      #pragma unroll
      for (int gx = 0; gx < 14; ++gx) {
        float v = wy0 * (wxa[gx] * r0[xo0[gx]] + wxb[gx] * r0[xo1[gx]]) +
                  wy1 * (wxa[gx] * r1[xo0[gx]] + wxb[gx] * r1[xo1[gx]]);
        mm[gx >> 1] = fmaxf(mm[gx >> 1], v);
      }
    }
    #pragma unroll
    for (int ow = 0; ow < 7; ++ow)
      out[((size_t)n * C_CH + c) * 49 + oh * 7 + ow] = mm[ow];
  }
}

extern "C" void kernel_launch(void* const* d_in, const int* in_sizes, int n_in,
                              void* d_out, int out_size, void* d_ws,
                              size_t ws_size, hipStream_t stream) {
  const float* f0 = (const float*)d_in[0];
  const float* f1 = (const float*)d_in[1];
  const float* f2 = (const float*)d_in[2];
  const float* f3 = (const float*)d_in[3];
  const float* props = (const float*)d_in[4];
  float* out = (float*)d_out;
  int N = in_sizes[4] / 4;

  const size_t needed = (size_t)87040 * C_CH * sizeof(__hip_bfloat16);  // 44.6MB
  if (ws_size >= needed) {
    unsigned short* tf = (unsigned short*)d_ws;
    void* args[8];
    args[0] = (void*)&f0;
    args[1] = (void*)&f1;
    args[2] = (void*)&f2;
    args[3] = (void*)&f3;
    args[4] = (void*)&props;
    args[5] = (void*)&tf;
    args[6] = (void*)&out;
    args[7] = (void*)&N;
    hipError_t err = hipLaunchCooperativeKernel(
        reinterpret_cast<const void*>(fused_all), dim3(FGRID), dim3(512), args,
        0, stream);
    if (err != hipSuccess) {  // cooperative unsupported -> proven 2-kernel path
      transpose_all<<<5440, 256, 0, stream>>>(f0, f1, f2, f3,
                                              (__hip_bfloat16*)d_ws);
      roi_bf16<<<N, 512, 0, stream>>>(tf, props, out);
    }
  } else {
    roi_fallback<<<dim3(N, 4), 64, 0, stream>>>(f0, f1, f2, f3, props, out);
  }
}

// Round 3
// 146.696 us; speedup vs baseline: 1.5597x; 1.5597x over previous
//
#include <hip/hip_runtime.h>
#include <hip/hip_bf16.h>
#include <math.h>

#define C_CH 256

// ---------------------------------------------------------------------------
// Transpose all 4 FPN levels from fp32 (C,H,W) to bf16 (H*W, C) in d_ws.
// R0-proven geometry: 64-spatial x 64-channel tiles, 256 threads, 16.6 KB LDS
// -> 8+ blocks/CU, 5440 independent blocks. (R1's full-row variant and R2's
// cooperative fusion both regressed: occupancy/parallelism loss dominated any
// write-granularity gain. Counters show no over-fetch -> keep this body.)
// ---------------------------------------------------------------------------
__global__ __launch_bounds__(256) void transpose_all(
    const float* __restrict__ f0, const float* __restrict__ f1,
    const float* __restrict__ f2, const float* __restrict__ f3,
    __hip_bfloat16* __restrict__ tf) {
  __shared__ float tile[64][65];
  const int b = blockIdx.x;  // 5440 total
  const float* src;
  int S, lg;
  size_t dstoff;
  int sb;
  if (b < 4096) {        // level0: 1024 sp-tiles x 4 cgroups
    src = f0; S = 65536; lg = 10; dstoff = 0;     sb = b;
  } else if (b < 5120) { // level1: 256 x 4
    src = f1; S = 16384; lg = 8;  dstoff = 65536; sb = b - 4096;
  } else if (b < 5376) { // level2: 64 x 4
    src = f2; S = 4096;  lg = 6;  dstoff = 81920; sb = b - 5120;
  } else {               // level3: 16 x 4
    src = f3; S = 1024;  lg = 4;  dstoff = 86016; sb = b - 5376;
  }
  const int nsp_m1 = (1 << lg) - 1;
  const int s0 = (sb & nsp_m1) * 64;
  const int c0 = (sb >> lg) * 64;

  const int t = threadIdx.x;
  {  // load: float4 along spatial, 256B coalesced runs per channel row
    const int cl = t >> 4;          // 0..15
    const int sp4 = (t & 15) * 4;   // 0..60
    #pragma unroll
    for (int j = 0; j < 4; ++j) {
      const int c = cl + 16 * j;
      const float4 v = *(const float4*)(src + (size_t)(c0 + c) * S + s0 + sp4);
      tile[c][sp4 + 0] = v.x;
      tile[c][sp4 + 1] = v.y;
      tile[c][sp4 + 2] = v.z;
      tile[c][sp4 + 3] = v.w;
    }
  }
  __syncthreads();
  {  // store: gather 4 channels (2-way LDS, free), ushort4 stores, 128B runs
    const int spl = t >> 4;         // 0..15
    const int c4 = (t & 15) * 4;    // 0..60
    __hip_bfloat16* dst = tf + (dstoff + (size_t)s0) * C_CH + c0;
    #pragma unroll
    for (int j = 0; j < 4; ++j) {
      const int sp = spl + 16 * j;
      union { ushort4 u; __hip_bfloat16 h[4]; } p;
      p.h[0] = __float2bfloat16(tile[c4 + 0][sp]);
      p.h[1] = __float2bfloat16(tile[c4 + 1][sp]);
      p.h[2] = __float2bfloat16(tile[c4 + 2][sp]);
      p.h[3] = __float2bfloat16(tile[c4 + 3][sp]);
      *(ushort4*)(dst + (size_t)sp * C_CH + c4) = p.u;
    }
  }
}

__device__ __forceinline__ float bfu(unsigned short s) {
  union { unsigned u; float f; } v;
  v.u = (unsigned)s << 16;
  return v.f;
}

// ---------------------------------------------------------------------------
// ROI Align + 2x2 max pool, transposed bf16 path.
// One 512-thread block (8 waves) per proposal; wave = output row oh; lane
// covers channels 4L..4L+3 via ushort4 gathers.
// R3 changes (counter-driven, R2 profile):
//  (1) obuf XOR-swizzle: slot q' = (c>>2) ^ p, row stride 256. The epilogue's
//      scalar reads previously stepped p -> bank stride 4 -> 8-way conflict
//      (2.5M SQ_LDS_BANK_CONFLICT cycles measured). XOR by p's low bits
//      rotates the bank group per p -> ~2-way (free). Compute-side float4
//      writes: lanes' q' = lane^p is a permutation -> still 2-way, free.
//  (2) software-pipelined gather loop: prefetch gx+1's 8 ushort4 loads while
//      computing gx (ROI phase is latency-bound: 16 waves/CU is the grid-
//      imposed cap, so latency hiding must come from load ILP).
// ---------------------------------------------------------------------------
__global__ __launch_bounds__(512) void roi_bf16(
    const unsigned short* __restrict__ tf,
    const float* __restrict__ proposals, float* __restrict__ out) {
  __shared__ int xo0[14], xo1[14], yo0[14], yo1[14];
  __shared__ float wxa[14], wxb[14], wya[14], wyb[14];
  __shared__ float obuf[49 * 256];  // 49 KB, XOR-swizzled 16B slots

  const int n = blockIdx.x;
  const int t = threadIdx.x;
  const int lane = t & 63;
  const int w = t >> 6;  // wave id 0..7

  const float px1 = proposals[n * 4 + 0];
  const float py1 = proposals[n * 4 + 1];
  const float px2 = proposals[n * 4 + 2];
  const float py2 = proposals[n * 4 + 3];
  float lt = 2.0f + log2f(sqrtf((px2 - px1) * (py2 - py1)) / 224.0f);
  int lvl = (int)floorf(lt);
  lvl = lvl < 0 ? 0 : (lvl > 3 ? 3 : lvl);

  const float scales[4] = {0.25f, 0.125f, 0.0625f, 0.03125f};
  const int sizes[4] = {256, 128, 64, 32};
  const int offs[4] = {0, 65536, 81920, 86016};
  const float sc = scales[lvl];
  const int sz = sizes[lvl];

  const float bx1 = px1 * sc, by1 = py1 * sc;
  const float w_unit = ((px2 - px1) * sc / 7.0f) * 0.5f;
  const float h_unit = ((py2 - py1) * sc / 7.0f) * 0.5f;

  if (t < 14) {
    const int i = t;
    float x = bx1 + ((float)i + 0.5f) * w_unit;
    int xf = (int)floorf(x);
    int x0 = min(max(xf, 0), sz - 1);
    int x1 = min(max(xf + 1, 0), sz - 1);
    wxa[i] = (float)x1 - x;  // matches ref incl. clipped extrapolation
    wxb[i] = x - (float)x0;
    xo0[i] = x0 * C_CH;
    xo1[i] = x1 * C_CH;
  } else if (t >= 64 && t < 78) {
    const int i = t - 64;
    float y = by1 + ((float)i + 0.5f) * h_unit;
    int yf = (int)floorf(y);
    int y0 = min(max(yf, 0), sz - 1);
    int y1 = min(max(yf + 1, 0), sz - 1);
    wya[i] = (float)y1 - y;
    wyb[i] = y - (float)y0;
    yo0[i] = y0 * sz * C_CH;
    yo1[i] = y1 * sz * C_CH;
  }
  __syncthreads();

  if (w < 7) {  // wave-uniform: waves 0-6 compute, wave 7 only helps store
    const int oh = w;
    const int gy0 = 2 * oh, gy1 = 2 * oh + 1;
    const unsigned short* base = tf + (size_t)offs[lvl] * C_CH + lane * 4;
    const unsigned short* r00 = base + yo0[gy0];
    const unsigned short* r01 = base + yo1[gy0];
    const unsigned short* r10 = base + yo0[gy1];
    const unsigned short* r11 = base + yo1[gy1];
    const float wy0a = wya[gy0], wy0b = wyb[gy0];
    const float wy1a = wya[gy1], wy1b = wyb[gy1];

    float mm[7][4];
    #pragma unroll
    for (int j = 0; j < 7; ++j)
      #pragma unroll
      for (int k = 0; k < 4; ++k) mm[j][k] = -INFINITY;

    // Software-pipelined gather: prefetch gx+1 while computing gx.
    ushort4 nA0, nA1, nB0, nB1, nC0, nC1, nD0, nD1;
    {
      const int xa = xo0[0], xb = xo1[0];
      nA0 = *(const ushort4*)(r00 + xa);
      nA1 = *(const ushort4*)(r00 + xb);
      nB0 = *(const ushort4*)(r01 + xa);
      nB1 = *(const ushort4*)(r01 + xb);
      nC0 = *(const ushort4*)(r10 + xa);
      nC1 = *(const ushort4*)(r10 + xb);
      nD0 = *(const ushort4*)(r11 + xa);
      nD1 = *(const ushort4*)(r11 + xb);
    }
    #pragma unroll
    for (int gx = 0; gx < 14; ++gx) {
      const ushort4 A0 = nA0, A1 = nA1, B0 = nB0, B1 = nB1;
      const ushort4 C0 = nC0, C1 = nC1, D0 = nD0, D1 = nD1;
      if (gx < 13) {  // compile-time (fully unrolled)
        const int xa = xo0[gx + 1], xb = xo1[gx + 1];
        nA0 = *(const ushort4*)(r00 + xa);
        nA1 = *(const ushort4*)(r00 + xb);
        nB0 = *(const ushort4*)(r01 + xa);
        nB1 = *(const ushort4*)(r01 + xb);
        nC0 = *(const ushort4*)(r10 + xa);
        nC1 = *(const ushort4*)(r10 + xb);
        nD0 = *(const ushort4*)(r11 + xa);
        nD1 = *(const ushort4*)(r11 + xb);
      }
      const float fa = wxa[gx], fb = wxb[gx];
      const int j = gx >> 1;
      const unsigned short* a0 = (const unsigned short*)&A0;
      const unsigned short* a1 = (const unsigned short*)&A1;
      const unsigned short* b0 = (const unsigned short*)&B0;
      const unsigned short* b1 = (const unsigned short*)&B1;
      const unsigned short* c0 = (const unsigned short*)&C0;
      const unsigned short* c1 = (const unsigned short*)&C1;
      const unsigned short* d0 = (const unsigned short*)&D0;
      const unsigned short* d1 = (const unsigned short*)&D1;
      #pragma unroll
      for (int k = 0; k < 4; ++k) {
        const float h00 = fa * bfu(a0[k]) + fb * bfu(a1[k]);
        const float h01 = fa * bfu(b0[k]) + fb * bfu(b1[k]);
        const float va = wy0a * h00 + wy0b * h01;
        const float h10 = fa * bfu(c0[k]) + fb * bfu(c1[k]);
        const float h11 = fa * bfu(d0[k]) + fb * bfu(d1[k]);
        const float vb = wy1a * h10 + wy1b * h11;
        mm[j][k] = fmaxf(mm[j][k], fmaxf(va, vb));
      }
    }

    // Stage: obuf row p = oh*7+ow, slot (c>>2)^p. Wave writes a permuted
    // contiguous 1 KB row per ow -> 2-way ds_write_b128 (free).
    #pragma unroll
    for (int ow = 0; ow < 7; ++ow) {
      const int p = oh * 7 + ow;
      float4 v = make_float4(mm[ow][0], mm[ow][1], mm[ow][2], mm[ow][3]);
      *(float4*)&obuf[p * 256 + ((lane ^ p) & 63) * 4] = v;
    }
  }
  __syncthreads();

  // Contiguous coalesced block store: out[n*12544 + i], i = c*49 + p.
  // Swizzled read: bank group rotates with p -> ~2-way instead of 8-way.
  float* ob = out + (size_t)n * (C_CH * 49);
  for (int i = t; i < C_CH * 49; i += 512) {
    const unsigned c = (unsigned)i / 49u;
    const unsigned p = (unsigned)i - c * 49u;
    const unsigned q = ((c >> 2) ^ p) & 63u;
    ob[i] = obuf[p * 256 + q * 4 + (c & 3)];
  }
}

// ---------------------------------------------------------------------------
// Fallback (no workspace): direct (C,H,W) reads. Correctness-only path.
// ---------------------------------------------------------------------------
__global__ __launch_bounds__(64) void roi_fallback(
    const float* __restrict__ f0, const float* __restrict__ f1,
    const float* __restrict__ f2, const float* __restrict__ f3,
    const float* __restrict__ proposals, float* __restrict__ out) {
  __shared__ int xo0[14], xo1[14], yo0[14], yo1[14];
  __shared__ float wxa[14], wxb[14], wya[14], wyb[14];
  const int n = blockIdx.x;
  const int cblk = blockIdx.y;
  const int lane = threadIdx.x;
  const int c = cblk * 64 + lane;
  const float px1 = proposals[n * 4 + 0];
  const float py1 = proposals[n * 4 + 1];
  const float px2 = proposals[n * 4 + 2];
  const float py2 = proposals[n * 4 + 3];
  float lt = 2.0f + log2f(sqrtf((px2 - px1) * (py2 - py1)) / 224.0f);
  int lvl = (int)floorf(lt);
  lvl = lvl < 0 ? 0 : (lvl > 3 ? 3 : lvl);
  const float scales[4] = {0.25f, 0.125f, 0.0625f, 0.03125f};
  const int sizes[4] = {256, 128, 64, 32};
  const float sc = scales[lvl];
  const int sz = sizes[lvl];
  const float bx1 = px1 * sc, by1 = py1 * sc;
  const float w_unit = ((px2 - px1) * sc / 7.0f) * 0.5f;
  const float h_unit = ((py2 - py1) * sc / 7.0f) * 0.5f;
  if (lane < 14) {
    float x = bx1 + ((float)lane + 0.5f) * w_unit;
    int xf = (int)floorf(x);
    int x0 = min(max(xf, 0), sz - 1);
    int x1 = min(max(xf + 1, 0), sz - 1);
    wxa[lane] = (float)x1 - x;
    wxb[lane] = x - (float)x0;
    xo0[lane] = x0;
    xo1[lane] = x1;
  } else if (lane >= 32 && lane < 46) {
    const int i = lane - 32;
    float y = by1 + ((float)i + 0.5f) * h_unit;
    int yf = (int)floorf(y);
    int y0 = min(max(yf, 0), sz - 1);
    int y1 = min(max(yf + 1, 0), sz - 1);
    wya[i] = (float)y1 - y;
    wyb[i] = y - (float)y0;
    yo0[i] = y0 * sz;
    yo1[i] = y1 * sz;
  }
  __syncthreads();
  const float* fl = (lvl == 0) ? f0 : (lvl == 1) ? f1 : (lvl == 2) ? f2 : f3;
  const float* base = fl + (size_t)c * sz * sz;
  for (int oh = 0; oh < 7; ++oh) {
    float mm[7];
    #pragma unroll
    for (int ow = 0; ow < 7; ++ow) mm[ow] = -INFINITY;
    #pragma unroll
    for (int sy = 0; sy < 2; ++sy) {
      const int gy = oh * 2 + sy;
      const float* r0 = base + yo0[gy];
      const float* r1 = base + yo1[gy];
      const float wy0 = wya[gy], wy1 = wyb[gy];
      #pragma unroll
      for (int gx = 0; gx < 14; ++gx) {
        float v = wy0 * (wxa[gx] * r0[xo0[gx]] + wxb[gx] * r0[xo1[gx]]) +
                  wy1 * (wxa[gx] * r1[xo0[gx]] + wxb[gx] * r1[xo1[gx]]);
        mm[gx >> 1] = fmaxf(mm[gx >> 1], v);
      }
    }
    #pragma unroll
    for (int ow = 0; ow < 7; ++ow)
      out[((size_t)n * C_CH + c) * 49 + oh * 7 + ow] = mm[ow];
  }
}

extern "C" void kernel_launch(void* const* d_in, const int* in_sizes, int n_in,
                              void* d_out, int out_size, void* d_ws,
                              size_t ws_size, hipStream_t stream) {
  const float* f0 = (const float*)d_in[0];
  const float* f1 = (const float*)d_in[1];
  const float* f2 = (const float*)d_in[2];
  const float* f3 = (const float*)d_in[3];
  const float* props = (const float*)d_in[4];
  float* out = (float*)d_out;
  const int N = in_sizes[4] / 4;

  const size_t needed = (size_t)87040 * C_CH * sizeof(__hip_bfloat16);  // 44.6MB
  if (ws_size >= needed) {
    __hip_bfloat16* tf = (__hip_bfloat16*)d_ws;
    transpose_all<<<5440, 256, 0, stream>>>(f0, f1, f2, f3, tf);
    roi_bf16<<<N, 512, 0, stream>>>((const unsigned short*)tf, props, out);
  } else {
    roi_fallback<<<dim3(N, 4), 64, 0, stream>>>(f0, f1, f2, f3, props, out);
  }
}

// Round 4
// 141.476 us; speedup vs baseline: 1.6173x; 1.0369x over previous
//
#include <hip/hip_runtime.h>
#include <hip/hip_bf16.h>
#include <math.h>

#define C_CH 256

// ---------------------------------------------------------------------------
// Transpose all 4 FPN levels from fp32 (C,H,W) to bf16 (H*W, C) in d_ws.
// R0-proven geometry: 64-spatial x 64-channel tiles, 256 threads, 16.6 KB LDS
// -> 8+ blocks/CU, 5440 independent blocks. R2 fused counters proved this
// pattern has NO over-fetch (FETCH 79MB < ideal 89) and NO write
// amplification (WRITE == tf+out exactly) -> body kept verbatim.
// ---------------------------------------------------------------------------
__global__ __launch_bounds__(256) void transpose_all(
    const float* __restrict__ f0, const float* __restrict__ f1,
    const float* __restrict__ f2, const float* __restrict__ f3,
    __hip_bfloat16* __restrict__ tf) {
  __shared__ float tile[64][65];
  const int b = blockIdx.x;  // 5440 total
  const float* src;
  int S, lg;
  size_t dstoff;
  int sb;
  if (b < 4096) {        // level0: 1024 sp-tiles x 4 cgroups
    src = f0; S = 65536; lg = 10; dstoff = 0;     sb = b;
  } else if (b < 5120) { // level1: 256 x 4
    src = f1; S = 16384; lg = 8;  dstoff = 65536; sb = b - 4096;
  } else if (b < 5376) { // level2: 64 x 4
    src = f2; S = 4096;  lg = 6;  dstoff = 81920; sb = b - 5120;
  } else {               // level3: 16 x 4
    src = f3; S = 1024;  lg = 4;  dstoff = 86016; sb = b - 5376;
  }
  const int nsp_m1 = (1 << lg) - 1;
  const int s0 = (sb & nsp_m1) * 64;
  const int c0 = (sb >> lg) * 64;

  const int t = threadIdx.x;
  {  // load: float4 along spatial, 256B coalesced runs per channel row
    const int cl = t >> 4;          // 0..15
    const int sp4 = (t & 15) * 4;   // 0..60
    #pragma unroll
    for (int j = 0; j < 4; ++j) {
      const int c = cl + 16 * j;
      const float4 v = *(const float4*)(src + (size_t)(c0 + c) * S + s0 + sp4);
      tile[c][sp4 + 0] = v.x;
      tile[c][sp4 + 1] = v.y;
      tile[c][sp4 + 2] = v.z;
      tile[c][sp4 + 3] = v.w;
    }
  }
  __syncthreads();
  {  // store: gather 4 channels (2-way LDS, free), ushort4 stores, 128B runs
    const int spl = t >> 4;         // 0..15
    const int c4 = (t & 15) * 4;    // 0..60
    __hip_bfloat16* dst = tf + (dstoff + (size_t)s0) * C_CH + c0;
    #pragma unroll
    for (int j = 0; j < 4; ++j) {
      const int sp = spl + 16 * j;
      union { ushort4 u; __hip_bfloat16 h[4]; } p;
      p.h[0] = __float2bfloat16(tile[c4 + 0][sp]);
      p.h[1] = __float2bfloat16(tile[c4 + 1][sp]);
      p.h[2] = __float2bfloat16(tile[c4 + 2][sp]);
      p.h[3] = __float2bfloat16(tile[c4 + 3][sp]);
      *(ushort4*)(dst + (size_t)sp * C_CH + c4) = p.u;
    }
  }
}

__device__ __forceinline__ float bfu(unsigned short s) {
  union { unsigned u; float f; } v;
  v.u = (unsigned)s << 16;
  return v.f;
}

// ---------------------------------------------------------------------------
// ROI Align + 2x2 max pool, transposed bf16 path.
// R4 (counter-driven): the ROI phase is LATENCY-bound (R2 fused profile:
// VALUBusy 10%, occupancy 44%; grid previously capped occupancy at 2
// blocks/CU = 16 waves/CU). This round: 2x TLP via channel-split.
//   grid = 2N: block (n, half) covers channels half*128..half*128+127.
//   Lane covers 2 channels (ushort2 gathers, still one 256-B wave
//   transaction per load); obuf halves to 24.5 KB -> LDS allows 6 blocks/CU,
//   grid gives 4 -> 32 waves/CU (2x). __launch_bounds__(512,8) keeps
//   VGPR <= 64 so 8 waves/SIMD actually fit.
// Depth-1 software prefetch kept from R3.
// ---------------------------------------------------------------------------
__global__ __launch_bounds__(512, 8) void roi_bf16(
    const unsigned short* __restrict__ tf,
    const float* __restrict__ proposals, float* __restrict__ out) {
  __shared__ int xo0[14], xo1[14], yo0[14], yo1[14];
  __shared__ float wxa[14], wxb[14], wya[14], wyb[14];
  __shared__ float obuf[49 * 128];  // 24.5 KB, XOR-swizzled 8-B slots

  const int n = blockIdx.x >> 1;
  const int half = blockIdx.x & 1;
  const int t = threadIdx.x;
  const int lane = t & 63;
  const int w = t >> 6;  // wave id 0..7

  const float px1 = proposals[n * 4 + 0];
  const float py1 = proposals[n * 4 + 1];
  const float px2 = proposals[n * 4 + 2];
  const float py2 = proposals[n * 4 + 3];
  float lt = 2.0f + log2f(sqrtf((px2 - px1) * (py2 - py1)) / 224.0f);
  int lvl = (int)floorf(lt);
  lvl = lvl < 0 ? 0 : (lvl > 3 ? 3 : lvl);

  const float scales[4] = {0.25f, 0.125f, 0.0625f, 0.03125f};
  const int sizes[4] = {256, 128, 64, 32};
  const int offs[4] = {0, 65536, 81920, 86016};
  const float sc = scales[lvl];
  const int sz = sizes[lvl];

  const float bx1 = px1 * sc, by1 = py1 * sc;
  const float w_unit = ((px2 - px1) * sc / 7.0f) * 0.5f;
  const float h_unit = ((py2 - py1) * sc / 7.0f) * 0.5f;

  if (t < 14) {
    const int i = t;
    float x = bx1 + ((float)i + 0.5f) * w_unit;
    int xf = (int)floorf(x);
    int x0 = min(max(xf, 0), sz - 1);
    int x1 = min(max(xf + 1, 0), sz - 1);
    wxa[i] = (float)x1 - x;  // matches ref incl. clipped extrapolation
    wxb[i] = x - (float)x0;
    xo0[i] = x0 * C_CH;
    xo1[i] = x1 * C_CH;
  } else if (t >= 64 && t < 78) {
    const int i = t - 64;
    float y = by1 + ((float)i + 0.5f) * h_unit;
    int yf = (int)floorf(y);
    int y0 = min(max(yf, 0), sz - 1);
    int y1 = min(max(yf + 1, 0), sz - 1);
    wya[i] = (float)y1 - y;
    wyb[i] = y - (float)y0;
    yo0[i] = y0 * sz * C_CH;
    yo1[i] = y1 * sz * C_CH;
  }
  __syncthreads();

  if (w < 7) {  // wave-uniform: waves 0-6 compute, wave 7 only helps store
    const int oh = w;
    const int gy0 = 2 * oh, gy1 = 2 * oh + 1;
    // lane covers channels half*128 + lane*2 (+0,+1)
    const unsigned short* base =
        tf + (size_t)offs[lvl] * C_CH + half * 128 + lane * 2;
    const unsigned short* r00 = base + yo0[gy0];
    const unsigned short* r01 = base + yo1[gy0];
    const unsigned short* r10 = base + yo0[gy1];
    const unsigned short* r11 = base + yo1[gy1];
    const float wy0a = wya[gy0], wy0b = wyb[gy0];
    const float wy1a = wya[gy1], wy1b = wyb[gy1];

    float mm[7][2];
    #pragma unroll
    for (int j = 0; j < 7; ++j) {
      mm[j][0] = -INFINITY;
      mm[j][1] = -INFINITY;
    }

    // Software-pipelined gather: prefetch gx+1 while computing gx.
    ushort2 nA0, nA1, nB0, nB1, nC0, nC1, nD0, nD1;
    {
      const int xa = xo0[0], xb = xo1[0];
      nA0 = *(const ushort2*)(r00 + xa);
      nA1 = *(const ushort2*)(r00 + xb);
      nB0 = *(const ushort2*)(r01 + xa);
      nB1 = *(const ushort2*)(r01 + xb);
      nC0 = *(const ushort2*)(r10 + xa);
      nC1 = *(const ushort2*)(r10 + xb);
      nD0 = *(const ushort2*)(r11 + xa);
      nD1 = *(const ushort2*)(r11 + xb);
    }
    #pragma unroll
    for (int gx = 0; gx < 14; ++gx) {
      const ushort2 A0 = nA0, A1 = nA1, B0 = nB0, B1 = nB1;
      const ushort2 C0 = nC0, C1 = nC1, D0 = nD0, D1 = nD1;
      if (gx < 13) {  // compile-time (fully unrolled)
        const int xa = xo0[gx + 1], xb = xo1[gx + 1];
        nA0 = *(const ushort2*)(r00 + xa);
        nA1 = *(const ushort2*)(r00 + xb);
        nB0 = *(const ushort2*)(r01 + xa);
        nB1 = *(const ushort2*)(r01 + xb);
        nC0 = *(const ushort2*)(r10 + xa);
        nC1 = *(const ushort2*)(r10 + xb);
        nD0 = *(const ushort2*)(r11 + xa);
        nD1 = *(const ushort2*)(r11 + xb);
      }
      const float fa = wxa[gx], fb = wxb[gx];
      const int j = gx >> 1;
      const unsigned short* a0 = (const unsigned short*)&A0;
      const unsigned short* a1 = (const unsigned short*)&A1;
      const unsigned short* b0 = (const unsigned short*)&B0;
      const unsigned short* b1 = (const unsigned short*)&B1;
      const unsigned short* c0 = (const unsigned short*)&C0;
      const unsigned short* c1 = (const unsigned short*)&C1;
      const unsigned short* d0 = (const unsigned short*)&D0;
      const unsigned short* d1 = (const unsigned short*)&D1;
      #pragma unroll
      for (int k = 0; k < 2; ++k) {
        const float h00 = fa * bfu(a0[k]) + fb * bfu(a1[k]);
        const float h01 = fa * bfu(b0[k]) + fb * bfu(b1[k]);
        const float va = wy0a * h00 + wy0b * h01;
        const float h10 = fa * bfu(c0[k]) + fb * bfu(c1[k]);
        const float h11 = fa * bfu(d0[k]) + fb * bfu(d1[k]);
        const float vb = wy1a * h10 + wy1b * h11;
        mm[j][k] = fmaxf(mm[j][k], fmaxf(va, vb));
      }
    }

    // Stage: obuf row p = oh*7+ow, 8-B slot (lane^p)&63 holds local channels
    // (2*lane, 2*lane+1). XOR keeps both write (float2, permutation -> exact
    // 2-way, free) and the epilogue's p-striding reads spread across banks.
    #pragma unroll
    for (int ow = 0; ow < 7; ++ow) {
      const int p = oh * 7 + ow;
      float2 v = make_float2(mm[ow][0], mm[ow][1]);
      *(float2*)&obuf[p * 128 + ((lane ^ p) & 63) * 2] = v;
    }
  }
  __syncthreads();

  // Contiguous coalesced block store of this half's 25 KB:
  // out[n*12544 + half*6272 + i], i = c_local*49 + p.
  float* ob = out + (size_t)n * (C_CH * 49) + half * (128 * 49);
  for (int i = t; i < 128 * 49; i += 512) {
    const unsigned cl = (unsigned)i / 49u;
    const unsigned p = (unsigned)i - cl * 49u;
    const unsigned q = ((cl >> 1) ^ p) & 63u;
    ob[i] = obuf[p * 128 + q * 2 + (cl & 1)];
  }
}

// ---------------------------------------------------------------------------
// Fallback (no workspace): direct (C,H,W) reads. Correctness-only path.
// ---------------------------------------------------------------------------
__global__ __launch_bounds__(64) void roi_fallback(
    const float* __restrict__ f0, const float* __restrict__ f1,
    const float* __restrict__ f2, const float* __restrict__ f3,
    const float* __restrict__ proposals, float* __restrict__ out) {
  __shared__ int xo0[14], xo1[14], yo0[14], yo1[14];
  __shared__ float wxa[14], wxb[14], wya[14], wyb[14];
  const int n = blockIdx.x;
  const int cblk = blockIdx.y;
  const int lane = threadIdx.x;
  const int c = cblk * 64 + lane;
  const float px1 = proposals[n * 4 + 0];
  const float py1 = proposals[n * 4 + 1];
  const float px2 = proposals[n * 4 + 2];
  const float py2 = proposals[n * 4 + 3];
  float lt = 2.0f + log2f(sqrtf((px2 - px1) * (py2 - py1)) / 224.0f);
  int lvl = (int)floorf(lt);
  lvl = lvl < 0 ? 0 : (lvl > 3 ? 3 : lvl);
  const float scales[4] = {0.25f, 0.125f, 0.0625f, 0.03125f};
  const int sizes[4] = {256, 128, 64, 32};
  const float sc = scales[lvl];
  const int sz = sizes[lvl];
  const float bx1 = px1 * sc, by1 = py1 * sc;
  const float w_unit = ((px2 - px1) * sc / 7.0f) * 0.5f;
  const float h_unit = ((py2 - py1) * sc / 7.0f) * 0.5f;
  if (lane < 14) {
    float x = bx1 + ((float)lane + 0.5f) * w_unit;
    int xf = (int)floorf(x);
    int x0 = min(max(xf, 0), sz - 1);
    int x1 = min(max(xf + 1, 0), sz - 1);
    wxa[lane] = (float)x1 - x;
    wxb[lane] = x - (float)x0;
    xo0[lane] = x0;
    xo1[lane] = x1;
  } else if (lane >= 32 && lane < 46) {
    const int i = lane - 32;
    float y = by1 + ((float)i + 0.5f) * h_unit;
    int yf = (int)floorf(y);
    int y0 = min(max(yf, 0), sz - 1);
    int y1 = min(max(yf + 1, 0), sz - 1);
    wya[i] = (float)y1 - y;
    wyb[i] = y - (float)y0;
    yo0[i] = y0 * sz;
    yo1[i] = y1 * sz;
  }
  __syncthreads();
  const float* fl = (lvl == 0) ? f0 : (lvl == 1) ? f1 : (lvl == 2) ? f2 : f3;
  const float* base = fl + (size_t)c * sz * sz;
  for (int oh = 0; oh < 7; ++oh) {
    float mm[7];
    #pragma unroll
    for (int ow = 0; ow < 7; ++ow) mm[ow] = -INFINITY;
    #pragma unroll
    for (int sy = 0; sy < 2; ++sy) {
      const int gy = oh * 2 + sy;
      const float* r0 = base + yo0[gy];
      const float* r1 = base + yo1[gy];
      const float wy0 = wya[gy], wy1 = wyb[gy];
      #pragma unroll
      for (int gx = 0; gx < 14; ++gx) {
        float v = wy0 * (wxa[gx] * r0[xo0[gx]] + wxb[gx] * r0[xo1[gx]]) +
                  wy1 * (wxa[gx] * r1[xo0[gx]] + wxb[gx] * r1[xo1[gx]]);
        mm[gx >> 1] = fmaxf(mm[gx >> 1], v);
      }
    }
    #pragma unroll
    for (int ow = 0; ow < 7; ++ow)
      out[((size_t)n * C_CH + c) * 49 + oh * 7 + ow] = mm[ow];
  }
}

extern "C" void kernel_launch(void* const* d_in, const int* in_sizes, int n_in,
                              void* d_out, int out_size, void* d_ws,
                              size_t ws_size, hipStream_t stream) {
  const float* f0 = (const float*)d_in[0];
  const float* f1 = (const float*)d_in[1];
  const float* f2 = (const float*)d_in[2];
  const float* f3 = (const float*)d_in[3];
  const float* props = (const float*)d_in[4];
  float* out = (float*)d_out;
  const int N = in_sizes[4] / 4;

  const size_t needed = (size_t)87040 * C_CH * sizeof(__hip_bfloat16);  // 44.6MB
  if (ws_size >= needed) {
    __hip_bfloat16* tf = (__hip_bfloat16*)d_ws;
    transpose_all<<<5440, 256, 0, stream>>>(f0, f1, f2, f3, tf);
    roi_bf16<<<2 * N, 512, 0, stream>>>((const unsigned short*)tf, props, out);
  } else {
    roi_fallback<<<dim3(N, 4), 64, 0, stream>>>(f0, f1, f2, f3, props, out);
  }
}

// Round 5
// 139.670 us; speedup vs baseline: 1.6382x; 1.0129x over previous
//
#include <hip/hip_runtime.h>
#include <hip/hip_bf16.h>
#include <math.h>

#define C_CH 256

typedef const __attribute__((address_space(1))) void* gas_t;
typedef __attribute__((address_space(3))) void* las_t;

// ---------------------------------------------------------------------------
// Transpose all 4 FPN levels from fp32 (C,H,W) to bf16 (H*W, C) in d_ws.
// R5 (counter/model-driven): load phase now uses width-16 global_load_lds
// (HBM -> LDS DMA, no VGPR round-trip, no ds_write stream; guide m97: +67%
// on staging). gload_lds writes linearly (base + lane*16), so the old [64][65]
// pad is replaced by a LINEAR [64][64] tile with the swizzle moved to the
// per-lane GLOBAL column (m173/T2 pattern): lane (c, s) loads global column
// 4*(s ^ (c>>2)) -- same 256B row, same cache lines, coalescing unchanged.
// Store phase reads word c*64 + ((sp>>2)^(c>>2))*4 + (sp&3): 64 lanes hit 32
// banks at exactly 2-way (free, m136). Geometry unchanged: 5440 blocks x 256
// thr, 16 KB LDS, 8 blocks/CU.
// ---------------------------------------------------------------------------
__global__ __launch_bounds__(256) void transpose_all(
    const float* __restrict__ f0, const float* __restrict__ f1,
    const float* __restrict__ f2, const float* __restrict__ f3,
    __hip_bfloat16* __restrict__ tf) {
  __shared__ float tile[64 * 64];  // linear, swizzled via global pre-permute
  const int b = blockIdx.x;  // 5440 total
  const float* src;
  int S, lg;
  size_t dstoff;
  int sb;
  if (b < 4096) {        // level0: 1024 sp-tiles x 4 cgroups
    src = f0; S = 65536; lg = 10; dstoff = 0;     sb = b;
  } else if (b < 5120) { // level1: 256 x 4
    src = f1; S = 16384; lg = 8;  dstoff = 65536; sb = b - 4096;
  } else if (b < 5376) { // level2: 64 x 4
    src = f2; S = 4096;  lg = 6;  dstoff = 81920; sb = b - 5120;
  } else {               // level3: 16 x 4
    src = f3; S = 1024;  lg = 4;  dstoff = 86016; sb = b - 5376;
  }
  const int nsp_m1 = (1 << lg) - 1;
  const int s0 = (sb & nsp_m1) * 64;
  const int c0 = (sb >> lg) * 64;

  const int t = threadIdx.x;
  const int lane = t & 63;
  const int wv = t >> 6;  // wave 0..3

  {  // load: one global_load_lds_dwordx4 per wave per j (fire-and-forget).
     // lane covers channel row c = 4*wv + 16*j + (lane>>4), physical 16B slot
     // s = lane&15; global column pre-swizzled by K = c>>2 = wv + 4*j
     // (wave-uniform), so LDS stays linear while the logical layout is
     // XOR-swizzled for the read phase.
    #pragma unroll
    for (int j = 0; j < 4; ++j) {
      const int c = 4 * wv + 16 * j + (lane >> 4);
      const int K = (wv + 4 * j) & 15;
      const int slot = (lane & 15) ^ K;
      const float* g = src + (size_t)(c0 + c) * S + s0 + slot * 4;
      float* l = &tile[(4 * wv + 16 * j) * 64];  // wave-uniform base
      __builtin_amdgcn_global_load_lds((gas_t)g, (las_t)l, 16, 0, 0);
    }
  }
  __syncthreads();  // drains vmcnt -> all DMA writes visible
  {  // store: gather 4 channels (2-way LDS, free), ushort4 stores, 128B runs
    const int spl = t >> 4;         // 0..15
    const int i16 = t & 15;
    const int c4 = i16 * 4;         // 0..60
    __hip_bfloat16* dst = tf + (dstoff + (size_t)s0) * C_CH + c0;
    #pragma unroll
    for (int j = 0; j < 4; ++j) {
      const int sp = spl + 16 * j;
      const int sl = sp >> 2;  // logical slot
      union { ushort4 u; __hip_bfloat16 h[4]; } p;
      #pragma unroll
      for (int k = 0; k < 4; ++k) {
        const int c = c4 + k;  // c>>2 == i16
        p.h[k] = __float2bfloat16(tile[c * 64 + ((sl ^ i16) << 2) + (sp & 3)]);
      }
      *(ushort4*)(dst + (size_t)sp * C_CH + c4) = p.u;
    }
  }
}

__device__ __forceinline__ float bfu(unsigned short s) {
  union { unsigned u; float f; } v;
  v.u = (unsigned)s << 16;
  return v.f;
}

// ---------------------------------------------------------------------------
// ROI Align + 2x2 max pool, transposed bf16 path. (R4 body, unchanged —
// channel-split 2x TLP won -5.2 us; kept verbatim for clean attribution.)
// ---------------------------------------------------------------------------
__global__ __launch_bounds__(512, 8) void roi_bf16(
    const unsigned short* __restrict__ tf,
    const float* __restrict__ proposals, float* __restrict__ out) {
  __shared__ int xo0[14], xo1[14], yo0[14], yo1[14];
  __shared__ float wxa[14], wxb[14], wya[14], wyb[14];
  __shared__ float obuf[49 * 128];  // 24.5 KB, XOR-swizzled 8-B slots

  const int n = blockIdx.x >> 1;
  const int half = blockIdx.x & 1;
  const int t = threadIdx.x;
  const int lane = t & 63;
  const int w = t >> 6;  // wave id 0..7

  const float px1 = proposals[n * 4 + 0];
  const float py1 = proposals[n * 4 + 1];
  const float px2 = proposals[n * 4 + 2];
  const float py2 = proposals[n * 4 + 3];
  float lt = 2.0f + log2f(sqrtf((px2 - px1) * (py2 - py1)) / 224.0f);
  int lvl = (int)floorf(lt);
  lvl = lvl < 0 ? 0 : (lvl > 3 ? 3 : lvl);

  const float scales[4] = {0.25f, 0.125f, 0.0625f, 0.03125f};
  const int sizes[4] = {256, 128, 64, 32};
  const int offs[4] = {0, 65536, 81920, 86016};
  const float sc = scales[lvl];
  const int sz = sizes[lvl];

  const float bx1 = px1 * sc, by1 = py1 * sc;
  const float w_unit = ((px2 - px1) * sc / 7.0f) * 0.5f;
  const float h_unit = ((py2 - py1) * sc / 7.0f) * 0.5f;

  if (t < 14) {
    const int i = t;
    float x = bx1 + ((float)i + 0.5f) * w_unit;
    int xf = (int)floorf(x);
    int x0 = min(max(xf, 0), sz - 1);
    int x1 = min(max(xf + 1, 0), sz - 1);
    wxa[i] = (float)x1 - x;  // matches ref incl. clipped extrapolation
    wxb[i] = x - (float)x0;
    xo0[i] = x0 * C_CH;
    xo1[i] = x1 * C_CH;
  } else if (t >= 64 && t < 78) {
    const int i = t - 64;
    float y = by1 + ((float)i + 0.5f) * h_unit;
    int yf = (int)floorf(y);
    int y0 = min(max(yf, 0), sz - 1);
    int y1 = min(max(yf + 1, 0), sz - 1);
    wya[i] = (float)y1 - y;
    wyb[i] = y - (float)y0;
    yo0[i] = y0 * sz * C_CH;
    yo1[i] = y1 * sz * C_CH;
  }
  __syncthreads();

  if (w < 7) {  // wave-uniform: waves 0-6 compute, wave 7 only helps store
    const int oh = w;
    const int gy0 = 2 * oh, gy1 = 2 * oh + 1;
    // lane covers channels half*128 + lane*2 (+0,+1)
    const unsigned short* base =
        tf + (size_t)offs[lvl] * C_CH + half * 128 + lane * 2;
    const unsigned short* r00 = base + yo0[gy0];
    const unsigned short* r01 = base + yo1[gy0];
    const unsigned short* r10 = base + yo0[gy1];
    const unsigned short* r11 = base + yo1[gy1];
    const float wy0a = wya[gy0], wy0b = wyb[gy0];
    const float wy1a = wya[gy1], wy1b = wyb[gy1];

    float mm[7][2];
    #pragma unroll
    for (int j = 0; j < 7; ++j) {
      mm[j][0] = -INFINITY;
      mm[j][1] = -INFINITY;
    }

    // Software-pipelined gather: prefetch gx+1 while computing gx.
    ushort2 nA0, nA1, nB0, nB1, nC0, nC1, nD0, nD1;
    {
      const int xa = xo0[0], xb = xo1[0];
      nA0 = *(const ushort2*)(r00 + xa);
      nA1 = *(const ushort2*)(r00 + xb);
      nB0 = *(const ushort2*)(r01 + xa);
      nB1 = *(const ushort2*)(r01 + xb);
      nC0 = *(const ushort2*)(r10 + xa);
      nC1 = *(const ushort2*)(r10 + xb);
      nD0 = *(const ushort2*)(r11 + xa);
      nD1 = *(const ushort2*)(r11 + xb);
    }
    #pragma unroll
    for (int gx = 0; gx < 14; ++gx) {
      const ushort2 A0 = nA0, A1 = nA1, B0 = nB0, B1 = nB1;
      const ushort2 C0 = nC0, C1 = nC1, D0 = nD0, D1 = nD1;
      if (gx < 13) {  // compile-time (fully unrolled)
        const int xa = xo0[gx + 1], xb = xo1[gx + 1];
        nA0 = *(const ushort2*)(r00 + xa);
        nA1 = *(const ushort2*)(r00 + xb);
        nB0 = *(const ushort2*)(r01 + xa);
        nB1 = *(const ushort2*)(r01 + xb);
        nC0 = *(const ushort2*)(r10 + xa);
        nC1 = *(const ushort2*)(r10 + xb);
        nD0 = *(const ushort2*)(r11 + xa);
        nD1 = *(const ushort2*)(r11 + xb);
      }
      const float fa = wxa[gx], fb = wxb[gx];
      const int j = gx >> 1;
      const unsigned short* a0 = (const unsigned short*)&A0;
      const unsigned short* a1 = (const unsigned short*)&A1;
      const unsigned short* b0 = (const unsigned short*)&B0;
      const unsigned short* b1 = (const unsigned short*)&B1;
      const unsigned short* c0 = (const unsigned short*)&C0;
      const unsigned short* c1 = (const unsigned short*)&C1;
      const unsigned short* d0 = (const unsigned short*)&D0;
      const unsigned short* d1 = (const unsigned short*)&D1;
      #pragma unroll
      for (int k = 0; k < 2; ++k) {
        const float h00 = fa * bfu(a0[k]) + fb * bfu(a1[k]);
        const float h01 = fa * bfu(b0[k]) + fb * bfu(b1[k]);
        const float va = wy0a * h00 + wy0b * h01;
        const float h10 = fa * bfu(c0[k]) + fb * bfu(c1[k]);
        const float h11 = fa * bfu(d0[k]) + fb * bfu(d1[k]);
        const float vb = wy1a * h10 + wy1b * h11;
        mm[j][k] = fmaxf(mm[j][k], fmaxf(va, vb));
      }
    }

    // Stage: obuf row p = oh*7+ow, 8-B slot (lane^p)&63 holds local channels
    // (2*lane, 2*lane+1). XOR keeps both write (float2, permutation -> exact
    // 2-way, free) and the epilogue's p-striding reads spread across banks.
    #pragma unroll
    for (int ow = 0; ow < 7; ++ow) {
      const int p = oh * 7 + ow;
      float2 v = make_float2(mm[ow][0], mm[ow][1]);
      *(float2*)&obuf[p * 128 + ((lane ^ p) & 63) * 2] = v;
    }
  }
  __syncthreads();

  // Contiguous coalesced block store of this half's 25 KB:
  // out[n*12544 + half*6272 + i], i = c_local*49 + p.
  float* ob = out + (size_t)n * (C_CH * 49) + half * (128 * 49);
  for (int i = t; i < 128 * 49; i += 512) {
    const unsigned cl = (unsigned)i / 49u;
    const unsigned p = (unsigned)i - cl * 49u;
    const unsigned q = ((cl >> 1) ^ p) & 63u;
    ob[i] = obuf[p * 128 + q * 2 + (cl & 1)];
  }
}

// ---------------------------------------------------------------------------
// Fallback (no workspace): direct (C,H,W) reads. Correctness-only path.
// ---------------------------------------------------------------------------
__global__ __launch_bounds__(64) void roi_fallback(
    const float* __restrict__ f0, const float* __restrict__ f1,
    const float* __restrict__ f2, const float* __restrict__ f3,
    const float* __restrict__ proposals, float* __restrict__ out) {
  __shared__ int xo0[14], xo1[14], yo0[14], yo1[14];
  __shared__ float wxa[14], wxb[14], wya[14], wyb[14];
  const int n = blockIdx.x;
  const int cblk = blockIdx.y;
  const int lane = threadIdx.x;
  const int c = cblk * 64 + lane;
  const float px1 = proposals[n * 4 + 0];
  const float py1 = proposals[n * 4 + 1];
  const float px2 = proposals[n * 4 + 2];
  const float py2 = proposals[n * 4 + 3];
  float lt = 2.0f + log2f(sqrtf((px2 - px1) * (py2 - py1)) / 224.0f);
  int lvl = (int)floorf(lt);
  lvl = lvl < 0 ? 0 : (lvl > 3 ? 3 : lvl);
  const float scales[4] = {0.25f, 0.125f, 0.0625f, 0.03125f};
  const int sizes[4] = {256, 128, 64, 32};
  const float sc = scales[lvl];
  const int sz = sizes[lvl];
  const float bx1 = px1 * sc, by1 = py1 * sc;
  const float w_unit = ((px2 - px1) * sc / 7.0f) * 0.5f;
  const float h_unit = ((py2 - py1) * sc / 7.0f) * 0.5f;
  if (lane < 14) {
    float x = bx1 + ((float)lane + 0.5f) * w_unit;
    int xf = (int)floorf(x);
    int x0 = min(max(xf, 0), sz - 1);
    int x1 = min(max(xf + 1, 0), sz - 1);
    wxa[lane] = (float)x1 - x;
    wxb[lane] = x - (float)x0;
    xo0[lane] = x0;
    xo1[lane] = x1;
  } else if (lane >= 32 && lane < 46) {
    const int i = lane - 32;
    float y = by1 + ((float)i + 0.5f) * h_unit;
    int yf = (int)floorf(y);
    int y0 = min(max(yf, 0), sz - 1);
    int y1 = min(max(yf + 1, 0), sz - 1);
    wya[i] = (float)y1 - y;
    wyb[i] = y - (float)y0;
    yo0[i] = y0 * sz;
    yo1[i] = y1 * sz;
  }
  __syncthreads();
  const float* fl = (lvl == 0) ? f0 : (lvl == 1) ? f1 : (lvl == 2) ? f2 : f3;
  const float* base = fl + (size_t)c * sz * sz;
  for (int oh = 0; oh < 7; ++oh) {
    float mm[7];
    #pragma unroll
    for (int ow = 0; ow < 7; ++ow) mm[ow] = -INFINITY;
    #pragma unroll
    for (int sy = 0; sy < 2; ++sy) {
      const int gy = oh * 2 + sy;
      const float* r0 = base + yo0[gy];
      const float* r1 = base + yo1[gy];
      const float wy0 = wya[gy], wy1 = wyb[gy];
      #pragma unroll
      for (int gx = 0; gx < 14; ++gx) {
        float v = wy0 * (wxa[gx] * r0[xo0[gx]] + wxb[gx] * r0[xo1[gx]]) +
                  wy1 * (wxa[gx] * r1[xo0[gx]] + wxb[gx] * r1[xo1[gx]]);
        mm[gx >> 1] = fmaxf(mm[gx >> 1], v);
      }
    }
    #pragma unroll
    for (int ow = 0; ow < 7; ++ow)
      out[((size_t)n * C_CH + c) * 49 + oh * 7 + ow] = mm[ow];
  }
}

extern "C" void kernel_launch(void* const* d_in, const int* in_sizes, int n_in,
                              void* d_out, int out_size, void* d_ws,
                              size_t ws_size, hipStream_t stream) {
  const float* f0 = (const float*)d_in[0];
  const float* f1 = (const float*)d_in[1];
  const float* f2 = (const float*)d_in[2];
  const float* f3 = (const float*)d_in[3];
  const float* props = (const float*)d_in[4];
  float* out = (float*)d_out;
  const int N = in_sizes[4] / 4;

  const size_t needed = (size_t)87040 * C_CH * sizeof(__hip_bfloat16);  // 44.6MB
  if (ws_size >= needed) {
    __hip_bfloat16* tf = (__hip_bfloat16*)d_ws;
    transpose_all<<<5440, 256, 0, stream>>>(f0, f1, f2, f3, tf);
    roi_bf16<<<2 * N, 512, 0, stream>>>((const unsigned short*)tf, props, out);
  } else {
    roi_fallback<<<dim3(N, 4), 64, 0, stream>>>(f0, f1, f2, f3, props, out);
  }
}